// Round 10
// baseline (329.889 us; speedup 1.0000x reference)
//
#include <hip/hip_runtime.h>
#include <hip/hip_bf16.h>
#include <stdint.h>

typedef unsigned short u16;
typedef __attribute__((ext_vector_type(8))) __bf16 bf16x8;
typedef __attribute__((ext_vector_type(4))) __bf16 bf16x4;
typedef __attribute__((ext_vector_type(4))) float f32x4;

#define S_LEN 2048
#define NHEAD 16
#define HDIM 64
#define DMODEL 1024
#define NBATCH 4
#define MTOK (NBATCH * S_LEN)   // 8192

// ---------- helpers ----------
__device__ __forceinline__ u16 f2bf(float f) {
    uint32_t u = __float_as_uint(f);
    u += 0x7fffu + ((u >> 16) & 1u);   // RNE
    return (u16)(u >> 16);
}

// async global->LDS, 16B per lane; lds dest must be wave-uniform base (+lane*16)
__device__ __forceinline__ void gld_lds16(const u16* g, u16* l) {
    __builtin_amdgcn_global_load_lds(
        (const __attribute__((address_space(1))) void*)g,
        (__attribute__((address_space(3))) void*)l, 16, 0, 0);
}

// ---------- fused fp32 -> bf16 cast: all 7 tensors in one launch ----------
// R5 post-mortem: fusing this into the GEMM fails (compiler sinks the f32
// prefetch -> latency exposed + 2x fetch). Keep the separate streaming cast.
__global__ __launch_bounds__(256) void cast_all(
        const float* __restrict__ q, const float* __restrict__ k, const float* __restrict__ v,
        const float* __restrict__ wq, const float* __restrict__ wk,
        const float* __restrict__ wv, const float* __restrict__ wo,
        u16* __restrict__ xq, u16* __restrict__ xk, u16* __restrict__ xv,
        u16* __restrict__ wqb, u16* __restrict__ wkb, u16* __restrict__ wvb,
        u16* __restrict__ wob) {
    size_t idx4 = (size_t)blockIdx.x * 256 + threadIdx.x;   // float4 index
    const float* src;
    u16* dst;
    size_t off;
    if (idx4 < (size_t)3 << 21) {
        int t = (int)(idx4 >> 21);
        off = (idx4 & ((1u << 21) - 1)) * 4;
        src = (t == 0) ? q : (t == 1) ? k : v;
        dst = (t == 0) ? xq : (t == 1) ? xk : xv;
    } else {
        size_t w = idx4 - ((size_t)3 << 21);
        int t = (int)(w >> 18);
        off = (w & ((1u << 18) - 1)) * 4;
        src = (t == 0) ? wq : (t == 1) ? wk : (t == 2) ? wv : wo;
        dst = (t == 0) ? wqb : (t == 1) ? wkb : (t == 2) ? wvb : wob;
    }
    float4 val = *(const float4*)(src + off);
    ushort4 o;
    o.x = f2bf(val.x); o.y = f2bf(val.y); o.z = f2bf(val.z); o.w = f2bf(val.w);
    *(ushort4*)(dst + off) = o;
}

// ---------- GEMM: out[m,n] = sum_k A[m,k]*W[n,k] + bias[n] ----------
// R10: counted-vmcnt at HIGH occupancy — the untested quadrant.
// R7 failed at 1 block/CU (occupancy, not the mechanism). Here: BK=32 with
// 3 buffers = 48 KiB LDS -> 3 blocks/CU (12 waves/CU, +50% TLP vs R6's 8),
// 256 thr (4 waves, 64x64 out each, acc[4][4], 16 MFMA/K-step).
// Schedule (hand-verified):
//   prologue: STG(0,t0); STG(1,t1); vmcnt(4); barrier
//   iter t:   STG((bc+2)%3, t+2)   [4 glds/wave]
//             ds_read buf bc (8 x b128); 16 MFMA
//             vmcnt(4) [t+1 landed a full iter ago; t+2 stays in flight]
//             raw s_barrier (NO vmcnt(0) drain in the main loop — T4)
//   tails: t=NKT-2 -> vmcnt(0); t=NKT-1 -> no wait.
// Buffer reuse safe: buf of tile t re-staged at iter t+1 (after the barrier
// following t's last read); every read covered by stager's counted wait +
// an intervening barrier.
// BK=32 swizzle: 4 col8 slots/row (64B rows). Stage source col8 =
// (lane&3)^((lane>>3)&3) (16 rows/gld, 4 lanes/row); fragment read slot
// cA = quad^((l16>>1)&3). Bank aliasing <=2-way (free, m136): even/odd rows
// split 16-bank halves; within a half each slot-quad gets 2 lanes.
#define TM 128
#define TN 128
#define BK 32
#define NKT (DMODEL / BK)   // 32

__device__ __forceinline__ void gemm_body(const u16* __restrict__ A,
                                          const u16* __restrict__ W,
                                          const float* __restrict__ bias,
                                          void* __restrict__ outp, int mode,
                                          int m0, int n0) {
    __shared__ __align__(16) u16 As[3][TM * BK];
    __shared__ __align__(16) u16 Bs[3][TM * BK];
    const int tid  = threadIdx.x;
    const int lane = tid & 63;
    const int wv   = tid >> 6;
    const int l16  = lane & 15;
    const int quad = lane >> 4;
    const int wm   = (wv >> 1) * 64;
    const int wn   = (wv & 1) * 64;

    f32x4 acc[4][4];
#pragma unroll
    for (int i = 0; i < 4; i++)
#pragma unroll
        for (int j = 0; j < 4; j++) acc[i][j] = {};

    // staging: one gld covers 16 rows x 32 cols (64 lanes x 16B). 4 lanes/row.
    const int sr  = lane >> 2;                       // row within 16-row group
    const int sc3 = (lane & 3) ^ ((lane >> 3) & 3);  // swizzled source col8
    // wave wv stages rows [wv*32, wv*32+32) of A and B (2 glds each)
    const u16* gA = A + (size_t)(m0 + wv * 32 + sr) * DMODEL + sc3 * 8;
    const u16* gB = W + (size_t)(n0 + wv * 32 + sr) * DMODEL + sc3 * 8;
    const int lofs = wv * 32 * BK;                   // wave-uniform LDS offset

    // fragment-read swizzled col8 (full K=32 in one b128 per 16-row block)
    const int cA = quad ^ ((l16 >> 1) & 3);

#define STG(b, t) do { \
    gld_lds16(gA + (size_t)(t) * BK,                      &As[b][lofs]); \
    gld_lds16(gA + (size_t)(t) * BK + (size_t)16 * DMODEL, &As[b][lofs + 16 * BK]); \
    gld_lds16(gB + (size_t)(t) * BK,                      &Bs[b][lofs]); \
    gld_lds16(gB + (size_t)(t) * BK + (size_t)16 * DMODEL, &Bs[b][lofs + 16 * BK]); \
} while (0)

    // prologue: tiles 0 and 1 in flight; wait only for tile 0
    STG(0, 0);
    STG(1, 1);
    __builtin_amdgcn_s_waitcnt(0x0F74);   // vmcnt(4): tile0 landed
    __builtin_amdgcn_sched_barrier(0);
    __builtin_amdgcn_s_barrier();
    __builtin_amdgcn_sched_barrier(0);

    int bc = 0;   // buffer holding tile t
#pragma unroll 1
    for (int t = 0; t < NKT; ++t) {
        if (t + 2 < NKT) {
            int bs = bc + 2; if (bs >= 3) bs -= 3;
            STG(bs, t + 2);
        }
        __builtin_amdgcn_sched_barrier(0);   // pin stage-issue before compute

        const u16* Ab = &As[bc][0];
        const u16* Bb = &Bs[bc][0];
        bf16x8 af[4], bf[4];
#pragma unroll
        for (int i = 0; i < 4; i++)
            af[i] = *(const bf16x8*)(Ab + (wm + i * 16 + l16) * BK + cA * 8);
#pragma unroll
        for (int j = 0; j < 4; j++)
            bf[j] = *(const bf16x8*)(Bb + (wn + j * 16 + l16) * BK + cA * 8);
#pragma unroll
        for (int i = 0; i < 4; i++)
#pragma unroll
            for (int j = 0; j < 4; j++)
                acc[i][j] = __builtin_amdgcn_mfma_f32_16x16x32_bf16(af[i], bf[j], acc[i][j], 0, 0, 0);

        if (t + 2 < NKT) {
            __builtin_amdgcn_s_waitcnt(0x0F74);   // vmcnt(4): t+1 landed
        } else if (t + 1 < NKT) {
            __builtin_amdgcn_s_waitcnt(0x0F70);   // vmcnt(0): last tile landed
        }
        __builtin_amdgcn_sched_barrier(0);
        __builtin_amdgcn_s_barrier();
        __builtin_amdgcn_sched_barrier(0);
        if (++bc == 3) bc = 0;
    }
#undef STG

#pragma unroll
    for (int j = 0; j < 4; j++) {
        int n = n0 + wn + j * 16 + l16;
        float bv = bias[n];
#pragma unroll
        for (int i = 0; i < 4; i++) {
            int mbase = m0 + wm + i * 16 + quad * 4;
#pragma unroll
            for (int r = 0; r < 4; r++) {
                int m = mbase + r;
                float v = acc[i][j][r] + bv;
                if (mode == 2) {
                    ((float*)outp)[(size_t)m * DMODEL + n] = v;
                } else {
                    int b = m >> 11, s = m & (S_LEN - 1);
                    int h = n >> 6, d = n & 63;
                    u16* o = (u16*)outp;
                    size_t idx = (mode == 0)
                        ? ((((size_t)(b * NHEAD + h)) * S_LEN + s) * HDIM + d)
                        : ((((size_t)(b * NHEAD + h)) * HDIM + d) * S_LEN + s);
                    o[idx] = f2bf(v);
                }
            }
        }
    }
}

// XCD-locality swizzle: XCD (lid&7) owns m-blocks [8*xcd, 8*xcd+8) for ALL n.
__device__ __forceinline__ void gemm_coords(int& m0, int& n0) {
    const int lid = blockIdx.x + 8 * blockIdx.y;   // 0..511
    const int xcd = lid & 7;
    const int s   = lid >> 3;                      // 0..63
    n0 = (s & 7) * TN;
    m0 = ((s >> 3) + 8 * xcd) * TM;
}

__global__ __launch_bounds__(256) void gemm_qkv(
        const u16* __restrict__ xq, const u16* __restrict__ xk, const u16* __restrict__ xv,
        const u16* __restrict__ wq, const u16* __restrict__ wk, const u16* __restrict__ wv,
        const float* __restrict__ bq, const float* __restrict__ bk, const float* __restrict__ bv,
        u16* __restrict__ Qb, u16* __restrict__ Kb, u16* __restrict__ Vb) {
    int z = blockIdx.z;
    const u16* A   = (z == 0) ? xq : (z == 1) ? xk : xv;
    const u16* W   = (z == 0) ? wq : (z == 1) ? wk : wv;
    const float* b = (z == 0) ? bq : (z == 1) ? bk : bv;
    u16* out       = (z == 0) ? Qb : (z == 1) ? Kb : Vb;
    int m0, n0;
    gemm_coords(m0, n0);
    gemm_body(A, W, b, out, (z == 2) ? 1 : 0, m0, n0);
}

__global__ __launch_bounds__(256) void gemm_one(
        const u16* __restrict__ A, const u16* __restrict__ W,
        const float* __restrict__ bias, void* __restrict__ out, int mode) {
    int m0, n0;
    gemm_coords(m0, n0);
    gemm_body(A, W, bias, out, mode, m0, n0);
}

// ---------- flash attention (v6 = v5 + T5 setprio on MFMA clusters) ----------
// 1 q-tile (16 queries) per wave; 64-key tiles; block-cooperative K/V LDS
// staging double-buffered via global_load_lds; XOR-swizzled layout; fixed-max
// log2-domain softmax; row sums via ones-operand MFMA; {g, 31-g} pairing ->
// exactly 33 iters/block.
// v5: QK^T computed as mfma(K, Q) — C-output col=l16 is the QUERY, row the
// KEY -> 4 consecutive keys per lane per t -> 4 ds_write_b64 P-scatter with
// native cvt_pk casts. P LDS layout keeps the XOR-swizzle invariant so the
// pf0/pf1 fragment reads (and PV/osum/epilogue) are byte-identical.
// v6: s_setprio(1) around the QK^T and PV MFMA clusters (T5).
// R8 lesson: the half-fused single-sweep variant (v7) is neutral-to-worse —
// flash is VALU+MFMA-balanced, not drain-bound; keep v6.
__global__ __launch_bounds__(256, 4) void flash_kernel(
        const u16* __restrict__ Q, const u16* __restrict__ K,
        const u16* __restrict__ Vt, u16* __restrict__ AO) {
    __shared__ __align__(16) u16 Ksm[2][64 * 64];
    __shared__ __align__(16) u16 Vsm[2][64 * 64];
    __shared__ __align__(16) u16 Psm[4][16 * 64];

    const int tid  = threadIdx.x;
    const int wv   = tid >> 6;
    const int lane = tid & 63;
    const int l16  = lane & 15;
    const int quad = lane >> 4;

    // XCD-pinning: all 16 blocks of a bh share (linear id % 8)
    const int lid   = blockIdx.x + 16 * blockIdx.y;   // 0..1023
    const int xcd   = lid & 7;
    const int slot  = lid >> 3;                        // 0..127
    const int bh    = xcd + 8 * (slot >> 4);           // 0..63
    const int g_idx = slot & 15;                       // 0..15

    const int h    = bh & (NHEAD - 1);
    const int b    = bh >> 4;
    const bool fwd = (h < 8);
    const int sgn  = fwd ? 1 : -1;
    const float slope2 = __builtin_amdgcn_exp2f(-(float)((h & 7) + 1) * 0.5731203125901445f)
                         * 1.4426950408889634f;
    const float cL = 0.18033688011112042f;   // log2(e)/8

    const u16* Kg = K + (size_t)bh * S_LEN * HDIM;
    const u16* Vg = Vt + (size_t)bh * HDIM * S_LEN;

    // staging lane constants: 8 lanes per row, col16 = (lane&7) ^ (lane>>3)
    const int sr = lane >> 3;
    const int sc = (lane & 7) ^ sr;
    const int r0 = 16 * wv;          // this wave stages rows r0..r0+15

    // fragment-read swizzled col16
    const int cA = quad ^ (l16 & 7);          // global col16 = quad
    const int cB = (quad + 4) ^ (l16 & 7);    // global col16 = quad+4

    // ALiBi per-(t,r) in-tile offset (swapped layout: key=16t+4q+r, query=l16)
    float brt[4][4];
#pragma unroll
    for (int t = 0; t < 4; t++)
#pragma unroll
        for (int r = 0; r < 4; r++)
            brt[t][r] = slope2 * (float)(sgn * (16 * t + 4 * quad + r - l16)) - 16.0f;

    // P packed-write offsets (u16 units): row l16, one b64 per t
    int poff4[4];
#pragma unroll
    for (int t = 0; t < 4; t++)
        poff4[t] = l16 * 64 + (((2 * t + (quad >> 1)) ^ (l16 & 7)) * 8) + 4 * (quad & 1);

    bf16x8 ones;
#pragma unroll
    for (int j = 0; j < 8; j++) ones[j] = (__bf16)1.0f;

    const float dkq = slope2 * (float)(sgn * 64);

#pragma unroll 1
    for (int half = 0; half < 2; half++) {
        const int g  = half ? (31 - g_idx) : g_idx;    // 64-query group 0..31
        const int q0 = g * 64 + wv * 16;
        const u16* Qp = Q + ((size_t)bh * S_LEN + q0) * HDIM;
        const bf16x8 aq0 = *(const bf16x8*)(Qp + l16 * HDIM + quad * 8);
        const bf16x8 aq1 = *(const bf16x8*)(Qp + l16 * HDIM + 32 + quad * 8);

        f32x4 o[4], osum = {};
#pragma unroll
        for (int dt = 0; dt < 4; dt++) o[dt] = {};

        const int kt0 = fwd ? 0 : g;
        const int kt1 = fwd ? g : (S_LEN / 64 - 1);

        __syncthreads();   // previous half's readers done before overwrite
        // incremental staging pointers
        const u16* kg = Kg + ((size_t)(kt0 * 64) + r0 + sr) * 64 + sc * 8;
        const u16* vg = Vg + (size_t)(r0 + sr) * S_LEN + kt0 * 64 + sc * 8;
        gld_lds16(kg,              &Ksm[0][r0 * 64]);
        gld_lds16(kg + 8 * 64,     &Ksm[0][(r0 + 8) * 64]);
        gld_lds16(vg,              &Vsm[0][r0 * 64]);
        gld_lds16(vg + 8 * S_LEN,  &Vsm[0][(r0 + 8) * 64]);
        kg += 64 * 64;
        vg += 64;

        float kq = slope2 * (float)(sgn * (kt0 * 64 - q0));

        int buf = 0;
        for (int kt = kt0; kt <= kt1; ++kt) {
            __builtin_amdgcn_s_waitcnt(0x0F70);   // vmcnt(0): buf staged
            __syncthreads();
            if (kt < kt1) {   // stage next tile into the other buffer
                gld_lds16(kg,             &Ksm[buf ^ 1][r0 * 64]);
                gld_lds16(kg + 8 * 64,    &Ksm[buf ^ 1][(r0 + 8) * 64]);
                gld_lds16(vg,             &Vsm[buf ^ 1][r0 * 64]);
                gld_lds16(vg + 8 * S_LEN, &Vsm[buf ^ 1][(r0 + 8) * 64]);
                kg += 64 * 64;
                vg += 64;
            }
            const u16* Ks = &Ksm[buf][0];
            const u16* Vs = &Vsm[buf][0];

            // QK^T from LDS — swapped operands: A=K rows, B=Q rows
            f32x4 st[4];
            __builtin_amdgcn_s_setprio(1);
#pragma unroll
            for (int t = 0; t < 4; t++) {
                const u16* kp = Ks + (16 * t + l16) * 64;
                bf16x8 k0 = *(const bf16x8*)(kp + cA * 8);
                bf16x8 k1 = *(const bf16x8*)(kp + cB * 8);
                f32x4 c = {};
                c = __builtin_amdgcn_mfma_f32_16x16x32_bf16(k0, aq0, c, 0, 0, 0);
                c = __builtin_amdgcn_mfma_f32_16x16x32_bf16(k1, aq1, c, 0, 0, 0);
                st[t] = c;
            }
            __builtin_amdgcn_s_setprio(0);

            float p[4][4];
            if (kt == g) {   // diagonal tile: explicit mask
                const int qg = q0 + l16;
#pragma unroll
                for (int t = 0; t < 4; t++)
#pragma unroll
                    for (int r = 0; r < 4; r++) {
                        const int kg2 = kt * 64 + 16 * t + 4 * quad + r;
                        const bool ok = fwd ? (kg2 <= qg) : (kg2 >= qg);
                        float s2 = fmaf(st[t][r], cL, brt[t][r] + kq);
                        p[t][r] = ok ? __builtin_amdgcn_exp2f(s2) : 0.0f;
                    }
            } else {
#pragma unroll
                for (int t = 0; t < 4; t++)
#pragma unroll
                    for (int r = 0; r < 4; r++)
                        p[t][r] = __builtin_amdgcn_exp2f(fmaf(st[t][r], cL, brt[t][r] + kq));
            }
            kq += dkq;

            // P row (4 consecutive keys per t) -> one b64 write per t
            u16* Pw = &Psm[wv][0];
#pragma unroll
            for (int t = 0; t < 4; t++) {
                bf16x4 pk;
                pk[0] = (__bf16)p[t][0];
                pk[1] = (__bf16)p[t][1];
                pk[2] = (__bf16)p[t][2];
                pk[3] = (__bf16)p[t][3];
                *(bf16x4*)(Pw + poff4[t]) = pk;
            }
            __builtin_amdgcn_s_waitcnt(0xC07F);   // lgkmcnt(0); wave-private
            bf16x8 pf0 = *(const bf16x8*)(&Pw[l16 * 64 + cA * 8]);
            bf16x8 pf1 = *(const bf16x8*)(&Pw[l16 * 64 + cB * 8]);

            // PV from LDS V
            __builtin_amdgcn_s_setprio(1);
#pragma unroll
            for (int dt = 0; dt < 4; dt++) {
                const u16* vp = Vs + (dt * 16 + l16) * 64;
                bf16x8 v0 = *(const bf16x8*)(vp + cA * 8);
                bf16x8 v1 = *(const bf16x8*)(vp + cB * 8);
                o[dt] = __builtin_amdgcn_mfma_f32_16x16x32_bf16(pf0, v0, o[dt], 0, 0, 0);
                o[dt] = __builtin_amdgcn_mfma_f32_16x16x32_bf16(pf1, v1, o[dt], 0, 0, 0);
            }
            osum = __builtin_amdgcn_mfma_f32_16x16x32_bf16(pf0, ones, osum, 0, 0, 0);
            osum = __builtin_amdgcn_mfma_f32_16x16x32_bf16(pf1, ones, osum, 0, 0, 0);
            __builtin_amdgcn_s_setprio(0);
            buf ^= 1;
        }

        // epilogue: AO[b, s, h*64+d] bf16
#pragma unroll
        for (int r = 0; r < 4; r++) {
            float inv = 1.0f / osum[r];
            int qg = q0 + quad * 4 + r;
            u16* op = AO + ((size_t)b * S_LEN + qg) * DMODEL + h * HDIM;
#pragma unroll
            for (int dt = 0; dt < 4; dt++)
                op[dt * 16 + l16] = f2bf(o[dt][r] * inv);
        }
    }
}

extern "C" void kernel_launch(void* const* d_in, const int* in_sizes, int n_in,
                              void* d_out, int out_size, void* d_ws, size_t ws_size,
                              hipStream_t stream) {
    const float* query = (const float*)d_in[0];
    const float* key   = (const float*)d_in[1];
    const float* value = (const float*)d_in[2];
    const float* Wq    = (const float*)d_in[3];
    const float* bq    = (const float*)d_in[4];
    const float* Wk    = (const float*)d_in[5];
    const float* bk    = (const float*)d_in[6];
    const float* Wv    = (const float*)d_in[7];
    const float* bv    = (const float*)d_in[8];
    const float* Wo    = (const float*)d_in[9];
    const float* bo    = (const float*)d_in[10];

    const size_t Xe = (size_t)MTOK * DMODEL;    // 2^23 elems
    const size_t We = (size_t)DMODEL * DMODEL;  // 2^20 elems
    u16* xq  = (u16*)d_ws;
    u16* xk  = xq + Xe;
    u16* xv  = xk + Xe;
    u16* wqb = xv + Xe;
    u16* wkb = wqb + We;
    u16* wvb = wkb + We;
    u16* wob = wvb + We;
    u16* Qb  = wob + We;
    u16* Kb  = Qb + Xe;
    u16* Vb  = Kb + Xe;   // transposed [B,H,D,S]
    u16* AO  = xq;        // alias: xq is dead once gemm_qkv completes

    cast_all<<<dim3(28672), dim3(256), 0, stream>>>(
        query, key, value, Wq, Wk, Wv, Wo,
        xq, xk, xv, wqb, wkb, wvb, wob);

    gemm_qkv<<<dim3(DMODEL / TN, MTOK / TM, 3), dim3(256), 0, stream>>>(
        xq, xk, xv, wqb, wkb, wvb, bq, bk, bv, Qb, Kb, Vb);

    flash_kernel<<<dim3(16, NBATCH * NHEAD), dim3(256), 0, stream>>>(Qb, Kb, Vb, AO);

    gemm_one<<<dim3(DMODEL / TN, MTOK / TM), dim3(256), 0, stream>>>(AO, wob, bo, d_out, 2);
}

// Round 12
// 305.985 us; speedup vs baseline: 1.0781x; 1.0781x over previous
//
#include <hip/hip_runtime.h>
#include <hip/hip_bf16.h>
#include <stdint.h>

typedef unsigned short u16;
typedef __attribute__((ext_vector_type(8))) __bf16 bf16x8;
typedef __attribute__((ext_vector_type(4))) __bf16 bf16x4;
typedef __attribute__((ext_vector_type(4))) float f32x4;

#define S_LEN 2048
#define NHEAD 16
#define HDIM 64
#define DMODEL 1024
#define NBATCH 4
#define MTOK (NBATCH * S_LEN)   // 8192

// ---------- helpers ----------
__device__ __forceinline__ u16 f2bf(float f) {
    uint32_t u = __float_as_uint(f);
    u += 0x7fffu + ((u >> 16) & 1u);   // RNE
    return (u16)(u >> 16);
}

// async global->LDS, 16B per lane; lds dest must be wave-uniform base (+lane*16)
__device__ __forceinline__ void gld_lds16(const u16* g, u16* l) {
    __builtin_amdgcn_global_load_lds(
        (const __attribute__((address_space(1))) void*)g,
        (__attribute__((address_space(3))) void*)l, 16, 0, 0);
}

// ---------- fused fp32 -> bf16 cast: all 7 tensors in one launch ----------
// R5 lesson: fusing this into the GEMM fails (compiler sinks the f32
// prefetch -> latency exposed + 2x fetch). Keep the separate streaming cast.
__global__ __launch_bounds__(256) void cast_all(
        const float* __restrict__ q, const float* __restrict__ k, const float* __restrict__ v,
        const float* __restrict__ wq, const float* __restrict__ wk,
        const float* __restrict__ wv, const float* __restrict__ wo,
        u16* __restrict__ xq, u16* __restrict__ xk, u16* __restrict__ xv,
        u16* __restrict__ wqb, u16* __restrict__ wkb, u16* __restrict__ wvb,
        u16* __restrict__ wob) {
    size_t idx4 = (size_t)blockIdx.x * 256 + threadIdx.x;   // float4 index
    const float* src;
    u16* dst;
    size_t off;
    if (idx4 < (size_t)3 << 21) {
        int t = (int)(idx4 >> 21);
        off = (idx4 & ((1u << 21) - 1)) * 4;
        src = (t == 0) ? q : (t == 1) ? k : v;
        dst = (t == 0) ? xq : (t == 1) ? xk : xv;
    } else {
        size_t w = idx4 - ((size_t)3 << 21);
        int t = (int)(w >> 18);
        off = (w & ((1u << 18) - 1)) * 4;
        src = (t == 0) ? wq : (t == 1) ? wk : (t == 2) ? wv : wo;
        dst = (t == 0) ? wqb : (t == 1) ? wkb : (t == 2) ? wvb : wob;
    }
    float4 val = *(const float4*)(src + off);
    ushort4 o;
    o.x = f2bf(val.x); o.y = f2bf(val.y); o.z = f2bf(val.z); o.w = f2bf(val.w);
    *(ushort4*)(dst + off) = o;
}

// ---------- GEMM: out[m,n] = sum_k A[m,k]*W[n,k] + bias[n] ----------
// R6-proven config (73.6 us, 700 TF, MfmaUtil ~29%, 0 bank conflicts):
// 128x128/BK=64, 256 thr (4 waves, 64x64 each), 64 KiB LDS -> 2 blocks/CU.
// Schedule-variant matrix measured this session (final):
//   vmcnt(0)+2buf/BK64 (this)           = 73.6 us  <- local optimum
//   8-phase 256^2 (R1)                  = 110  us  (1 blk/CU tail+lockstep)
//   counted+3buf/BK64 512thr (R7)       = 119  us  (1 blk/CU)
//   counted+3buf/BK32 3blk/CU (R10)     = 91   us  (2x barrier count, +17% fetch)
//   in-GEMM f32 cast (R5)               = 171  us  (prefetch sunk by compiler)
//   prologue: STAGE(buf0, k=0); vmcnt(0); barrier;
//   loop:     STAGE(buf^1, k+1); ds_read buf; 32 MFMA; vmcnt(0); barrier
// LDS layout = proven 64-col XOR swizzle (0 conflicts).
#define TM 128
#define TN 128
#define BK 64

__device__ __forceinline__ void gemm_body(const u16* __restrict__ A,
                                          const u16* __restrict__ W,
                                          const float* __restrict__ bias,
                                          void* __restrict__ outp, int mode,
                                          int m0, int n0) {
    __shared__ __align__(16) u16 As[2][TM * BK];
    __shared__ __align__(16) u16 Bs[2][TM * BK];
    const int tid  = threadIdx.x;
    const int lane = tid & 63;
    const int wv   = tid >> 6;
    const int l16  = lane & 15;
    const int quad = lane >> 4;
    const int wm   = (wv >> 1) * 64;
    const int wn   = (wv & 1) * 64;

    f32x4 acc[4][4];
#pragma unroll
    for (int i = 0; i < 4; i++)
#pragma unroll
        for (int j = 0; j < 4; j++) acc[i][j] = {};

    // staging: one gld covers 8 rows x 64 cols (64 lanes x 16B). 8 lanes/row.
    const int sr  = lane >> 3;                 // row within 8-row group
    const int sc7 = (lane & 7) ^ sr;           // swizzled source col8
    // wave wv stages rows [wv*32, wv*32+32) of A and B (4 glds each)
    const u16* gA = A + (size_t)(m0 + wv * 32 + sr) * DMODEL + sc7 * 8;
    const u16* gB = W + (size_t)(n0 + wv * 32 + sr) * DMODEL + sc7 * 8;
    const int lofs = wv * 32 * BK;             // wave-uniform LDS offset

    // fragment-read swizzled col8
    const int cA = quad ^ (l16 & 7);          // k in [0,32)
    const int cB = (quad + 4) ^ (l16 & 7);    // k in [32,64)

    // prologue: stage K-tile 0 into buf 0, drain, barrier
#pragma unroll
    for (int g = 0; g < 4; g++) {
        gld_lds16(gA + (size_t)(g * 8) * DMODEL, &As[0][lofs + g * 8 * BK]);
        gld_lds16(gB + (size_t)(g * 8) * DMODEL, &Bs[0][lofs + g * 8 * BK]);
    }
    __builtin_amdgcn_s_waitcnt(0x0F70);   // vmcnt(0)
    __syncthreads();

    int buf = 0;
    for (int kb = 0; kb < DMODEL; kb += BK) {
        const bool more = (kb + BK < DMODEL);
        if (more) {   // stage NEXT tile into the other buffer, issue-early
#pragma unroll
            for (int g = 0; g < 4; g++) {
                gld_lds16(gA + kb + BK + (size_t)(g * 8) * DMODEL,
                          &As[buf ^ 1][lofs + g * 8 * BK]);
                gld_lds16(gB + kb + BK + (size_t)(g * 8) * DMODEL,
                          &Bs[buf ^ 1][lofs + g * 8 * BK]);
            }
        }
        __builtin_amdgcn_sched_barrier(0);   // pin stage-issue before compute

        bf16x8 af0[4], af1[4], bf0[4], bf1[4];
#pragma unroll
        for (int i = 0; i < 4; i++) {
            const u16* ap = &As[buf][(wm + i * 16 + l16) * BK];
            af0[i] = *(const bf16x8*)(ap + cA * 8);
            af1[i] = *(const bf16x8*)(ap + cB * 8);
        }
#pragma unroll
        for (int j = 0; j < 4; j++) {
            const u16* bp = &Bs[buf][(wn + j * 16 + l16) * BK];
            bf0[j] = *(const bf16x8*)(bp + cA * 8);
            bf1[j] = *(const bf16x8*)(bp + cB * 8);
        }
#pragma unroll
        for (int i = 0; i < 4; i++)
#pragma unroll
            for (int j = 0; j < 4; j++)
                acc[i][j] = __builtin_amdgcn_mfma_f32_16x16x32_bf16(af0[i], bf0[j], acc[i][j], 0, 0, 0);
#pragma unroll
        for (int i = 0; i < 4; i++)
#pragma unroll
            for (int j = 0; j < 4; j++)
                acc[i][j] = __builtin_amdgcn_mfma_f32_16x16x32_bf16(af1[i], bf1[j], acc[i][j], 0, 0, 0);

        if (more) __builtin_amdgcn_s_waitcnt(0x0F70);   // vmcnt(0): next staged
        __syncthreads();
        buf ^= 1;
    }

#pragma unroll
    for (int j = 0; j < 4; j++) {
        int n = n0 + wn + j * 16 + l16;
        float bv = bias[n];
#pragma unroll
        for (int i = 0; i < 4; i++) {
            int mbase = m0 + wm + i * 16 + quad * 4;
#pragma unroll
            for (int r = 0; r < 4; r++) {
                int m = mbase + r;
                float v = acc[i][j][r] + bv;
                if (mode == 2) {
                    ((float*)outp)[(size_t)m * DMODEL + n] = v;
                } else {
                    int b = m >> 11, s = m & (S_LEN - 1);
                    int h = n >> 6, d = n & 63;
                    u16* o = (u16*)outp;
                    size_t idx = (mode == 0)
                        ? ((((size_t)(b * NHEAD + h)) * S_LEN + s) * HDIM + d)
                        : ((((size_t)(b * NHEAD + h)) * HDIM + d) * S_LEN + s);
                    o[idx] = f2bf(v);
                }
            }
        }
    }
}

// XCD-locality swizzle: XCD (lid&7) owns m-blocks [8*xcd, 8*xcd+8) for ALL n.
__device__ __forceinline__ void gemm_coords(int& m0, int& n0) {
    const int lid = blockIdx.x + 8 * blockIdx.y;   // 0..511
    const int xcd = lid & 7;
    const int s   = lid >> 3;                      // 0..63
    n0 = (s & 7) * TN;
    m0 = ((s >> 3) + 8 * xcd) * TM;
}

__global__ __launch_bounds__(256) void gemm_qkv(
        const u16* __restrict__ xq, const u16* __restrict__ xk, const u16* __restrict__ xv,
        const u16* __restrict__ wq, const u16* __restrict__ wk, const u16* __restrict__ wv,
        const float* __restrict__ bq, const float* __restrict__ bk, const float* __restrict__ bv,
        u16* __restrict__ Qb, u16* __restrict__ Kb, u16* __restrict__ Vb) {
    int z = blockIdx.z;
    const u16* A   = (z == 0) ? xq : (z == 1) ? xk : xv;
    const u16* W   = (z == 0) ? wq : (z == 1) ? wk : wv;
    const float* b = (z == 0) ? bq : (z == 1) ? bk : bv;
    u16* out       = (z == 0) ? Qb : (z == 1) ? Kb : Vb;
    int m0, n0;
    gemm_coords(m0, n0);
    gemm_body(A, W, b, out, (z == 2) ? 1 : 0, m0, n0);
}

__global__ __launch_bounds__(256) void gemm_one(
        const u16* __restrict__ A, const u16* __restrict__ W,
        const float* __restrict__ bias, void* __restrict__ out, int mode) {
    int m0, n0;
    gemm_coords(m0, n0);
    gemm_body(A, W, bias, out, mode, m0, n0);
}

// ---------- flash attention (v6 = v5 + T5 setprio on MFMA clusters) ----------
// 1 q-tile (16 queries) per wave; 64-key tiles; block-cooperative K/V LDS
// staging double-buffered via global_load_lds; XOR-swizzled layout; fixed-max
// log2-domain softmax; row sums via ones-operand MFMA; {g, 31-g} pairing ->
// exactly 33 iters/block.
// v5: QK^T computed as mfma(K, Q) — C-output col=l16 is the QUERY, row the
// KEY -> 4 consecutive keys per lane per t -> 4 ds_write_b64 P-scatter with
// native cvt_pk casts. P LDS layout keeps the XOR-swizzle invariant so the
// pf0/pf1 fragment reads (and PV/osum/epilogue) are byte-identical.
// v6: s_setprio(1) around the QK^T and PV MFMA clusters (T5).
// R8 lesson: the half-fused single-sweep variant (v7) is neutral-to-worse —
// flash is VALU+MFMA-balanced, not drain-bound; keep v6.
__global__ __launch_bounds__(256, 4) void flash_kernel(
        const u16* __restrict__ Q, const u16* __restrict__ K,
        const u16* __restrict__ Vt, u16* __restrict__ AO) {
    __shared__ __align__(16) u16 Ksm[2][64 * 64];
    __shared__ __align__(16) u16 Vsm[2][64 * 64];
    __shared__ __align__(16) u16 Psm[4][16 * 64];

    const int tid  = threadIdx.x;
    const int wv   = tid >> 6;
    const int lane = tid & 63;
    const int l16  = lane & 15;
    const int quad = lane >> 4;

    // XCD-pinning: all 16 blocks of a bh share (linear id % 8)
    const int lid   = blockIdx.x + 16 * blockIdx.y;   // 0..1023
    const int xcd   = lid & 7;
    const int slot  = lid >> 3;                        // 0..127
    const int bh    = xcd + 8 * (slot >> 4);           // 0..63
    const int g_idx = slot & 15;                       // 0..15

    const int h    = bh & (NHEAD - 1);
    const int b    = bh >> 4;
    const bool fwd = (h < 8);
    const int sgn  = fwd ? 1 : -1;
    const float slope2 = __builtin_amdgcn_exp2f(-(float)((h & 7) + 1) * 0.5731203125901445f)
                         * 1.4426950408889634f;
    const float cL = 0.18033688011112042f;   // log2(e)/8

    const u16* Kg = K + (size_t)bh * S_LEN * HDIM;
    const u16* Vg = Vt + (size_t)bh * HDIM * S_LEN;

    // staging lane constants: 8 lanes per row, col16 = (lane&7) ^ (lane>>3)
    const int sr = lane >> 3;
    const int sc = (lane & 7) ^ sr;
    const int r0 = 16 * wv;          // this wave stages rows r0..r0+15

    // fragment-read swizzled col16
    const int cA = quad ^ (l16 & 7);          // global col16 = quad
    const int cB = (quad + 4) ^ (l16 & 7);    // global col16 = quad+4

    // ALiBi per-(t,r) in-tile offset (swapped layout: key=16t+4q+r, query=l16)
    float brt[4][4];
#pragma unroll
    for (int t = 0; t < 4; t++)
#pragma unroll
        for (int r = 0; r < 4; r++)
            brt[t][r] = slope2 * (float)(sgn * (16 * t + 4 * quad + r - l16)) - 16.0f;

    // P packed-write offsets (u16 units): row l16, one b64 per t
    int poff4[4];
#pragma unroll
    for (int t = 0; t < 4; t++)
        poff4[t] = l16 * 64 + (((2 * t + (quad >> 1)) ^ (l16 & 7)) * 8) + 4 * (quad & 1);

    bf16x8 ones;
#pragma unroll
    for (int j = 0; j < 8; j++) ones[j] = (__bf16)1.0f;

    const float dkq = slope2 * (float)(sgn * 64);

#pragma unroll 1
    for (int half = 0; half < 2; half++) {
        const int g  = half ? (31 - g_idx) : g_idx;    // 64-query group 0..31
        const int q0 = g * 64 + wv * 16;
        const u16* Qp = Q + ((size_t)bh * S_LEN + q0) * HDIM;
        const bf16x8 aq0 = *(const bf16x8*)(Qp + l16 * HDIM + quad * 8);
        const bf16x8 aq1 = *(const bf16x8*)(Qp + l16 * HDIM + 32 + quad * 8);

        f32x4 o[4], osum = {};
#pragma unroll
        for (int dt = 0; dt < 4; dt++) o[dt] = {};

        const int kt0 = fwd ? 0 : g;
        const int kt1 = fwd ? g : (S_LEN / 64 - 1);

        __syncthreads();   // previous half's readers done before overwrite
        // incremental staging pointers
        const u16* kg = Kg + ((size_t)(kt0 * 64) + r0 + sr) * 64 + sc * 8;
        const u16* vg = Vg + (size_t)(r0 + sr) * S_LEN + kt0 * 64 + sc * 8;
        gld_lds16(kg,              &Ksm[0][r0 * 64]);
        gld_lds16(kg + 8 * 64,     &Ksm[0][(r0 + 8) * 64]);
        gld_lds16(vg,              &Vsm[0][r0 * 64]);
        gld_lds16(vg + 8 * S_LEN,  &Vsm[0][(r0 + 8) * 64]);
        kg += 64 * 64;
        vg += 64;

        float kq = slope2 * (float)(sgn * (kt0 * 64 - q0));

        int buf = 0;
        for (int kt = kt0; kt <= kt1; ++kt) {
            __builtin_amdgcn_s_waitcnt(0x0F70);   // vmcnt(0): buf staged
            __syncthreads();
            if (kt < kt1) {   // stage next tile into the other buffer
                gld_lds16(kg,             &Ksm[buf ^ 1][r0 * 64]);
                gld_lds16(kg + 8 * 64,    &Ksm[buf ^ 1][(r0 + 8) * 64]);
                gld_lds16(vg,             &Vsm[buf ^ 1][r0 * 64]);
                gld_lds16(vg + 8 * S_LEN, &Vsm[buf ^ 1][(r0 + 8) * 64]);
                kg += 64 * 64;
                vg += 64;
            }
            const u16* Ks = &Ksm[buf][0];
            const u16* Vs = &Vsm[buf][0];

            // QK^T from LDS — swapped operands: A=K rows, B=Q rows
            f32x4 st[4];
            __builtin_amdgcn_s_setprio(1);
#pragma unroll
            for (int t = 0; t < 4; t++) {
                const u16* kp = Ks + (16 * t + l16) * 64;
                bf16x8 k0 = *(const bf16x8*)(kp + cA * 8);
                bf16x8 k1 = *(const bf16x8*)(kp + cB * 8);
                f32x4 c = {};
                c = __builtin_amdgcn_mfma_f32_16x16x32_bf16(k0, aq0, c, 0, 0, 0);
                c = __builtin_amdgcn_mfma_f32_16x16x32_bf16(k1, aq1, c, 0, 0, 0);
                st[t] = c;
            }
            __builtin_amdgcn_s_setprio(0);

            float p[4][4];
            if (kt == g) {   // diagonal tile: explicit mask
                const int qg = q0 + l16;
#pragma unroll
                for (int t = 0; t < 4; t++)
#pragma unroll
                    for (int r = 0; r < 4; r++) {
                        const int kg2 = kt * 64 + 16 * t + 4 * quad + r;
                        const bool ok = fwd ? (kg2 <= qg) : (kg2 >= qg);
                        float s2 = fmaf(st[t][r], cL, brt[t][r] + kq);
                        p[t][r] = ok ? __builtin_amdgcn_exp2f(s2) : 0.0f;
                    }
            } else {
#pragma unroll
                for (int t = 0; t < 4; t++)
#pragma unroll
                    for (int r = 0; r < 4; r++)
                        p[t][r] = __builtin_amdgcn_exp2f(fmaf(st[t][r], cL, brt[t][r] + kq));
            }
            kq += dkq;

            // P row (4 consecutive keys per t) -> one b64 write per t
            u16* Pw = &Psm[wv][0];
#pragma unroll
            for (int t = 0; t < 4; t++) {
                bf16x4 pk;
                pk[0] = (__bf16)p[t][0];
                pk[1] = (__bf16)p[t][1];
                pk[2] = (__bf16)p[t][2];
                pk[3] = (__bf16)p[t][3];
                *(bf16x4*)(Pw + poff4[t]) = pk;
            }
            __builtin_amdgcn_s_waitcnt(0xC07F);   // lgkmcnt(0); wave-private
            bf16x8 pf0 = *(const bf16x8*)(&Pw[l16 * 64 + cA * 8]);
            bf16x8 pf1 = *(const bf16x8*)(&Pw[l16 * 64 + cB * 8]);

            // PV from LDS V
            __builtin_amdgcn_s_setprio(1);
#pragma unroll
            for (int dt = 0; dt < 4; dt++) {
                const u16* vp = Vs + (dt * 16 + l16) * 64;
                bf16x8 v0 = *(const bf16x8*)(vp + cA * 8);
                bf16x8 v1 = *(const bf16x8*)(vp + cB * 8);
                o[dt] = __builtin_amdgcn_mfma_f32_16x16x32_bf16(pf0, v0, o[dt], 0, 0, 0);
                o[dt] = __builtin_amdgcn_mfma_f32_16x16x32_bf16(pf1, v1, o[dt], 0, 0, 0);
            }
            osum = __builtin_amdgcn_mfma_f32_16x16x32_bf16(pf0, ones, osum, 0, 0, 0);
            osum = __builtin_amdgcn_mfma_f32_16x16x32_bf16(pf1, ones, osum, 0, 0, 0);
            __builtin_amdgcn_s_setprio(0);
            buf ^= 1;
        }

        // epilogue: AO[b, s, h*64+d] bf16
#pragma unroll
        for (int r = 0; r < 4; r++) {
            float inv = 1.0f / osum[r];
            int qg = q0 + quad * 4 + r;
            u16* op = AO + ((size_t)b * S_LEN + qg) * DMODEL + h * HDIM;
#pragma unroll
            for (int dt = 0; dt < 4; dt++)
                op[dt * 16 + l16] = f2bf(o[dt][r] * inv);
        }
    }
}

extern "C" void kernel_launch(void* const* d_in, const int* in_sizes, int n_in,
                              void* d_out, int out_size, void* d_ws, size_t ws_size,
                              hipStream_t stream) {
    const float* query = (const float*)d_in[0];
    const float* key   = (const float*)d_in[1];
    const float* value = (const float*)d_in[2];
    const float* Wq    = (const float*)d_in[3];
    const float* bq    = (const float*)d_in[4];
    const float* Wk    = (const float*)d_in[5];
    const float* bk    = (const float*)d_in[6];
    const float* Wv    = (const float*)d_in[7];
    const float* bv    = (const float*)d_in[8];
    const float* Wo    = (const float*)d_in[9];
    const float* bo    = (const float*)d_in[10];

    const size_t Xe = (size_t)MTOK * DMODEL;    // 2^23 elems
    const size_t We = (size_t)DMODEL * DMODEL;  // 2^20 elems
    u16* xq  = (u16*)d_ws;
    u16* xk  = xq + Xe;
    u16* xv  = xk + Xe;
    u16* wqb = xv + Xe;
    u16* wkb = wqb + We;
    u16* wvb = wkb + We;
    u16* wob = wvb + We;
    u16* Qb  = wob + We;
    u16* Kb  = Qb + Xe;
    u16* Vb  = Kb + Xe;   // transposed [B,H,D,S]
    u16* AO  = xq;        // alias: xq is dead once gemm_qkv completes

    cast_all<<<dim3(28672), dim3(256), 0, stream>>>(
        query, key, value, Wq, Wk, Wv, Wo,
        xq, xk, xv, wqb, wkb, wvb, wob);

    gemm_qkv<<<dim3(DMODEL / TN, MTOK / TM, 3), dim3(256), 0, stream>>>(
        xq, xk, xv, wqb, wkb, wvb, bq, bk, bv, Qb, Kb, Vb);

    flash_kernel<<<dim3(16, NBATCH * NHEAD), dim3(256), 0, stream>>>(Qb, Kb, Vb, AO);

    gemm_one<<<dim3(DMODEL / TN, MTOK / TM), dim3(256), 0, stream>>>(AO, wob, bo, d_out, 2);
}